// Round 1
// 163.061 us; speedup vs baseline: 1.3362x; 1.3362x over previous
//
#include <hip/hip_runtime.h>
#include <math.h>

#define NHID 128
#define TILE_E 128
#define LDK 264   // padded K stride in bf16 elems (fallback kernel)

typedef __bf16 bf16x8 __attribute__((ext_vector_type(8)));
typedef float f32x4 __attribute__((ext_vector_type(4)));
typedef unsigned short u16x8 __attribute__((ext_vector_type(8)));

__device__ __forceinline__ unsigned short f2bf(float f) {
  unsigned int u = __float_as_uint(f);
  u += 0x7fffu + ((u >> 16) & 1u);   // RNE
  return (unsigned short)(u >> 16);
}
__device__ __forceinline__ float bf2f(unsigned short u) {
  return __uint_as_float(((unsigned int)u) << 16);
}

// ============================================================================
// Phase 1: AB[node][0:128]  = inputs[node]·W1[0:128][:]   + bias1   (A half)
//          AB[node][128:256]= inputs[node]·W1[128:256][:]           (B half)
// bf16 output. Block = 256 thr (4 waves). Wave w owns output cols w*64..w*64+63.
// W1 fragments live in registers (loaded once); no barriers in the row loop.
// ============================================================================
__global__ __launch_bounds__(256)
void precompute_ab(const float* __restrict__ inputs,
                   const float* __restrict__ W1,
                   const float* __restrict__ bias1,
                   unsigned short* __restrict__ AB,
                   int n_nodes)
{
  // per-wave repack buffer: row stride 72 ushorts = 144 B (16B-multiple, bank-spread)
  __shared__ __align__(16) unsigned short sC[4][32][72];

  const int tid  = threadIdx.x;
  const int lane = tid & 63;
  const int w    = tid >> 6;          // wave 0..3 -> output cols w*64..+63
  const int m15  = lane & 15;
  const int quad = lane >> 4;
  const int koff = (w >> 1) * NHID;   // W1 row offset: 0 (A half) or 128 (B half)
  const int cW   = (w & 1) * 64;      // W1 col base within half

  // ---- W1 B-fragments in registers: bw[ks][nt], loop-invariant ----
  bf16x8 bw[4][4];
  #pragma unroll
  for (int ks = 0; ks < 4; ++ks) {
    #pragma unroll
    for (int nt = 0; nt < 4; ++nt) {
      u16x8 t;
      #pragma unroll
      for (int j = 0; j < 8; ++j)
        t[j] = f2bf(W1[(size_t)(koff + ks * 32 + quad * 8 + j) * NHID + cW + nt * 16 + m15]);
      bw[ks][nt] = __builtin_bit_cast(bf16x8, t);
    }
  }

  // bias1 folded into the A half only (waves 0,1)
  float bias[4];
  #pragma unroll
  for (int nt = 0; nt < 4; ++nt)
    bias[nt] = (w < 2) ? bias1[w * 64 + nt * 16 + m15] : 0.f;

  const int ntiles = (n_nodes + 31) >> 5;
  for (int t = blockIdx.x; t < ntiles; t += gridDim.x) {
    const int rowbase = t * 32;

    f32x4 acc[2][4];
    #pragma unroll
    for (int mt = 0; mt < 2; ++mt)
      #pragma unroll
      for (int nt = 0; nt < 4; ++nt)
        acc[mt][nt] = (f32x4){0.f, 0.f, 0.f, 0.f};

    #pragma unroll
    for (int ks = 0; ks < 4; ++ks) {
      bf16x8 a[2];
      #pragma unroll
      for (int mt = 0; mt < 2; ++mt) {
        int r = rowbase + mt * 16 + m15;
        if (r >= n_nodes) r = n_nodes - 1;
        const float* p = inputs + (size_t)r * NHID + ks * 32 + quad * 8;
        float4 lo = *(const float4*)p;
        float4 hi = *(const float4*)(p + 4);
        u16x8 tt;
        tt[0] = f2bf(lo.x); tt[1] = f2bf(lo.y); tt[2] = f2bf(lo.z); tt[3] = f2bf(lo.w);
        tt[4] = f2bf(hi.x); tt[5] = f2bf(hi.y); tt[6] = f2bf(hi.z); tt[7] = f2bf(hi.w);
        a[mt] = __builtin_bit_cast(bf16x8, tt);
      }
      #pragma unroll
      for (int mt = 0; mt < 2; ++mt)
        #pragma unroll
        for (int nt = 0; nt < 4; ++nt)
          acc[mt][nt] = __builtin_amdgcn_mfma_f32_16x16x32_bf16(a[mt], bw[ks][nt], acc[mt][nt], 0, 0, 0);
    }

    // ---- epilogue: +bias, cvt bf16, wave-local LDS repack, coalesced 16B stores ----
    // D layout: col = lane&15 (+nt*16), row = quad*4 + r (+mt*16)
    #pragma unroll
    for (int mt = 0; mt < 2; ++mt)
      #pragma unroll
      for (int nt = 0; nt < 4; ++nt)
        #pragma unroll
        for (int r = 0; r < 4; ++r)
          sC[w][mt * 16 + quad * 4 + r][nt * 16 + m15] = f2bf(acc[mt][nt][r] + bias[nt]);

    // wave-local write->read: compiler inserts lgkmcnt waits; no barrier needed
    #pragma unroll
    for (int p = 0; p < 4; ++p) {
      const int row  = p * 8 + (lane >> 3);
      const int node = rowbase + row;
      if (node < n_nodes) {
        u16x8 v = *(const u16x8*)&sC[w][row][(lane & 7) * 8];
        *(u16x8*)(AB + (size_t)node * 256 + w * 64 + (lane & 7) * 8) = v;
      }
    }
  }
}

// ============================================================================
// Phase 2: out[e] = sigmoid( relu(AB[x[e]][0:128] + AB[y[e]][128:256]) · W2 + b2 )
// 16 lanes per edge, 8 bf16 elems per lane, 2-edge unroll for gather ILP.
// Zero LDS, ~45 VGPR -> 8 blocks/CU -> 32 waves/CU of latency hiding.
// ============================================================================
__global__ __launch_bounds__(256, 4)
void edge_eval(const unsigned short* __restrict__ AB,
               const int* __restrict__ x_idx,
               const int* __restrict__ y_idx,
               const float* __restrict__ W2,
               const float* __restrict__ bias2,
               float* __restrict__ out,
               int n_edges)
{
  const int tid = threadIdx.x;
  const int g   = tid >> 4;   // group 0..15 within block
  const int l   = tid & 15;   // lane within group

  float w2[8];
  {
    float4 a = *(const float4*)(W2 + l * 8);
    float4 b = *(const float4*)(W2 + l * 8 + 4);
    w2[0] = a.x; w2[1] = a.y; w2[2] = a.z; w2[3] = a.w;
    w2[4] = b.x; w2[5] = b.y; w2[6] = b.z; w2[7] = b.w;
  }
  const float b2   = bias2[0];
  const int   last = n_edges - 1;
  const int   step = gridDim.x * 32;

  for (int base = blockIdx.x * 32; base < n_edges; base += step) {
    const int e0 = base + g;
    const int e1 = base + 16 + g;
    const int c0 = e0 < last ? e0 : last;
    const int c1 = e1 < last ? e1 : last;
    const int x0 = x_idx[c0], y0 = y_idx[c0];
    const int x1 = x_idx[c1], y1 = y_idx[c1];

    u16x8 ax0 = *(const u16x8*)(AB + (size_t)x0 * 256 + l * 8);
    u16x8 by0 = *(const u16x8*)(AB + (size_t)y0 * 256 + 128 + l * 8);
    u16x8 ax1 = *(const u16x8*)(AB + (size_t)x1 * 256 + l * 8);
    u16x8 by1 = *(const u16x8*)(AB + (size_t)y1 * 256 + 128 + l * 8);

    float s0 = 0.f, s1 = 0.f;
    #pragma unroll
    for (int j = 0; j < 8; ++j) {
      float h0 = bf2f(ax0[j]) + bf2f(by0[j]);
      float h1 = bf2f(ax1[j]) + bf2f(by1[j]);
      h0 = fmaxf(h0, 0.f);
      h1 = fmaxf(h1, 0.f);
      s0 = fmaf(h0, w2[j], s0);
      s1 = fmaf(h1, w2[j], s1);
    }
    #pragma unroll
    for (int d = 1; d < 16; d <<= 1) {
      s0 += __shfl_xor(s0, d);
      s1 += __shfl_xor(s1, d);
    }
    if (l == 0) {
      if (e0 < n_edges) out[e0] = 1.f / (1.f + __expf(-(s0 + b2)));
      if (e1 < n_edges) out[e1] = 1.f / (1.f + __expf(-(s1 + b2)));
    }
  }
}

// ============================================================================
// Fallback: previous fused kernel (used only if workspace is too small)
// ============================================================================
__global__ __launch_bounds__(256, 1)
void mlp_edge_decoder(const float* __restrict__ inputs,
                      const int* __restrict__ x_idx,
                      const int* __restrict__ y_idx,
                      const float* __restrict__ W1,
                      const float* __restrict__ bias1,
                      const float* __restrict__ W2,
                      const float* __restrict__ bias2,
                      float* __restrict__ out,
                      int n_edges)
{
  __shared__ __align__(16) unsigned short sW1T[NHID][LDK];
  __shared__ __align__(16) unsigned short sA[TILE_E][LDK];
  __shared__ float sB1[NHID];
  __shared__ float sW2[NHID];
  __shared__ float sRed[2][TILE_E];

  const int tid  = threadIdx.x;
  const int lane = tid & 63;
  const int wv   = tid >> 6;
  const int seg  = tid & 63;
  const int m15  = lane & 15;
  const int quad = lane >> 4;
  const int eh   = wv >> 1;
  const int ch   = wv & 1;

  for (int i = tid; i < 256 * NHID; i += 256) {
    int k = i >> 7;
    int n = i & 127;
    sW1T[n][k] = f2bf(W1[i]);
  }
  if (tid < NHID) { sB1[tid] = bias1[tid]; sW2[tid] = W2[tid]; }
  const float b2 = bias2[0];

  const int stride = gridDim.x * TILE_E;
  int ebase = blockIdx.x * TILE_E;

  float4 stage[32];
  #pragma unroll
  for (int j = 0; j < 32; ++j) {
    int e  = ebase + 4 * j + wv;
    int ec = (e < n_edges) ? e : 0;
    int idx = (seg < 32) ? x_idx[ec] : y_idx[ec];
    stage[j] = *(const float4*)(inputs + (size_t)idx * NHID + (seg & 31) * 4);
  }

  for (; ebase < n_edges; ebase += stride) {
    #pragma unroll
    for (int j = 0; j < 32; ++j) {
      int r = wv + 4 * j;
      ushort4 p;
      p.x = f2bf(stage[j].x);
      p.y = f2bf(stage[j].y);
      p.z = f2bf(stage[j].z);
      p.w = f2bf(stage[j].w);
      *(ushort4*)(&sA[r][seg * 4]) = p;
    }
    __syncthreads();

    {
      int nb = ebase + stride;
      if (nb < n_edges) {
        #pragma unroll
        for (int j = 0; j < 32; ++j) {
          int e  = nb + 4 * j + wv;
          int ec = (e < n_edges) ? e : 0;
          int idx = (seg < 32) ? x_idx[ec] : y_idx[ec];
          stage[j] = *(const float4*)(inputs + (size_t)idx * NHID + (seg & 31) * 4);
        }
      }
    }

    f32x4 acc[4][4];
    #pragma unroll
    for (int mt = 0; mt < 4; ++mt)
      #pragma unroll
      for (int nt = 0; nt < 4; ++nt)
        acc[mt][nt] = (f32x4){0.f, 0.f, 0.f, 0.f};

    #pragma unroll
    for (int ks = 0; ks < 8; ++ks) {
      bf16x8 af[4], bfr[4];
      #pragma unroll
      for (int mt = 0; mt < 4; ++mt)
        af[mt] = __builtin_bit_cast(bf16x8,
                   *(const u16x8*)(&sA[eh * 64 + mt * 16 + m15][ks * 32 + quad * 8]));
      #pragma unroll
      for (int nt = 0; nt < 4; ++nt)
        bfr[nt] = __builtin_bit_cast(bf16x8,
                   *(const u16x8*)(&sW1T[ch * 64 + nt * 16 + m15][ks * 32 + quad * 8]));
      #pragma unroll
      for (int mt = 0; mt < 4; ++mt)
        #pragma unroll
        for (int nt = 0; nt < 4; ++nt)
          acc[mt][nt] = __builtin_amdgcn_mfma_f32_16x16x32_bf16(af[mt], bfr[nt], acc[mt][nt], 0, 0, 0);
    }

    #pragma unroll
    for (int mt = 0; mt < 4; ++mt) {
      #pragma unroll
      for (int r = 0; r < 4; ++r) {
        float s = 0.f;
        #pragma unroll
        for (int nt = 0; nt < 4; ++nt) {
          int c = ch * 64 + nt * 16 + m15;
          float h = acc[mt][nt][r] + sB1[c];
          h = fmaxf(h, 0.f);
          s = fmaf(h, sW2[c], s);
        }
        s += __shfl_xor(s, 1);
        s += __shfl_xor(s, 2);
        s += __shfl_xor(s, 4);
        s += __shfl_xor(s, 8);
        if (m15 == 0) sRed[ch][eh * 64 + mt * 16 + quad * 4 + r] = s;
      }
    }
    __syncthreads();

    if (tid < TILE_E) {
      int e = ebase + tid;
      if (e < n_edges) {
        float s = sRed[0][tid] + sRed[1][tid] + b2;
        out[e] = 1.f / (1.f + __expf(-s));
      }
    }
  }
}

extern "C" void kernel_launch(void* const* d_in, const int* in_sizes, int n_in,
                              void* d_out, int out_size, void* d_ws, size_t ws_size,
                              hipStream_t stream) {
  const float* inputs = (const float*)d_in[0];
  const int*   x_idx  = (const int*)d_in[1];
  const int*   y_idx  = (const int*)d_in[2];
  const float* W1     = (const float*)d_in[3];
  const float* bias1  = (const float*)d_in[4];
  const float* W2     = (const float*)d_in[5];
  const float* bias2  = (const float*)d_in[6];
  float* out = (float*)d_out;
  const int n_edges = in_sizes[1];
  const int n_nodes = in_sizes[0] / NHID;

  const size_t need = (size_t)n_nodes * 256 * sizeof(unsigned short);
  if (d_ws != nullptr && ws_size >= need) {
    unsigned short* AB = (unsigned short*)d_ws;
    // Phase 1: node-level GEMM, 3125 row-tiles over 1024 blocks
    hipLaunchKernelGGL(precompute_ab, dim3(1024), dim3(256), 0, stream,
                       inputs, W1, bias1, AB, n_nodes);
    // Phase 2: streaming gather + epilogue, 8 blocks/CU
    hipLaunchKernelGGL(edge_eval, dim3(2048), dim3(256), 0, stream,
                       AB, x_idx, y_idx, W2, bias2, out, n_edges);
  } else {
    hipLaunchKernelGGL(mlp_edge_decoder, dim3(512), dim3(256), 0, stream,
                       inputs, x_idx, y_idx, W1, bias1, W2, bias2, out, n_edges);
  }
}

// Round 2
// 158.405 us; speedup vs baseline: 1.3755x; 1.0294x over previous
//
#include <hip/hip_runtime.h>
#include <math.h>

#define NHID 128
#define TILE_E 128
#define LDK 264   // padded K stride in bf16 elems (fallback kernel)

typedef __bf16 bf16x8 __attribute__((ext_vector_type(8)));
typedef float f32x4 __attribute__((ext_vector_type(4)));
typedef unsigned short u16x8 __attribute__((ext_vector_type(8)));

__device__ __forceinline__ unsigned short f2bf(float f) {
  unsigned int u = __float_as_uint(f);
  u += 0x7fffu + ((u >> 16) & 1u);   // RNE
  return (unsigned short)(u >> 16);
}
__device__ __forceinline__ float bf2f(unsigned short u) {
  return __uint_as_float(((unsigned int)u) << 16);
}

// ============================================================================
// Phase 1: AB[node][0:128]  = inputs[node]·W1[0:128][:]   + bias1   (A half)
//          AB[node][128:256]= inputs[node]·W1[128:256][:]           (B half)
// 16-row tiles, barrier-free register-prefetch pipeline: while tile t's
// MFMA+epilogue runs, tile t+1's 8 float4 loads are in flight.
// Wave w owns output cols w*64..w*64+63; W1 fragments pinned in registers.
// ============================================================================
__global__ __launch_bounds__(256)
void precompute_ab(const float* __restrict__ inputs,
                   const float* __restrict__ W1,
                   const float* __restrict__ bias1,
                   unsigned short* __restrict__ AB,
                   int n_nodes)
{
  // per-wave repack buffer: row stride 72 ushorts = 144 B (16B-multiple, bank-spread)
  __shared__ __align__(16) unsigned short sC[4][16][72];

  const int tid  = threadIdx.x;
  const int lane = tid & 63;
  const int w    = tid >> 6;          // wave 0..3 -> output cols w*64..+63
  const int m15  = lane & 15;
  const int quad = lane >> 4;
  const int koff = (w >> 1) * NHID;   // W1 row offset: 0 (A half) or 128 (B half)
  const int cW   = (w & 1) * 64;      // W1 col base within half

  // ---- W1 B-fragments in registers: bw[ks][nt], loop-invariant ----
  bf16x8 bw[4][4];
  #pragma unroll
  for (int ks = 0; ks < 4; ++ks) {
    #pragma unroll
    for (int nt = 0; nt < 4; ++nt) {
      u16x8 t;
      #pragma unroll
      for (int j = 0; j < 8; ++j)
        t[j] = f2bf(W1[(size_t)(koff + ks * 32 + quad * 8 + j) * NHID + cW + nt * 16 + m15]);
      bw[ks][nt] = __builtin_bit_cast(bf16x8, t);
    }
  }

  // bias1 folded into the A half only (waves 0,1)
  float bias[4];
  #pragma unroll
  for (int nt = 0; nt < 4; ++nt)
    bias[nt] = (w < 2) ? bias1[w * 64 + nt * 16 + m15] : 0.f;

  const int ntiles = (n_nodes + 15) >> 4;
  const int stride = gridDim.x;
  int t = blockIdx.x;

  // ---- prologue: load tile t into pf ----
  float4 pf[8];
  {
    int r = t * 16 + m15;
    if (r >= n_nodes) r = n_nodes - 1;
    const float* rp = inputs + (size_t)r * NHID + quad * 8;
    #pragma unroll
    for (int ks = 0; ks < 4; ++ks) {
      pf[2 * ks]     = *(const float4*)(rp + ks * 32);
      pf[2 * ks + 1] = *(const float4*)(rp + ks * 32 + 4);
    }
  }

  for (; t < ntiles; t += stride) {
    // ---- convert current tile fp32 -> bf16 fragments ----
    u16x8 af[4];
    #pragma unroll
    for (int ks = 0; ks < 4; ++ks) {
      u16x8 tt;
      tt[0] = f2bf(pf[2 * ks].x);     tt[1] = f2bf(pf[2 * ks].y);
      tt[2] = f2bf(pf[2 * ks].z);     tt[3] = f2bf(pf[2 * ks].w);
      tt[4] = f2bf(pf[2 * ks + 1].x); tt[5] = f2bf(pf[2 * ks + 1].y);
      tt[6] = f2bf(pf[2 * ks + 1].z); tt[7] = f2bf(pf[2 * ks + 1].w);
      af[ks] = tt;
    }

    // ---- issue next tile's loads now; they fly under MFMA+epilogue ----
    {
      int tn = t + stride;
      if (tn < ntiles) {
        int r = tn * 16 + m15;
        if (r >= n_nodes) r = n_nodes - 1;
        const float* rp = inputs + (size_t)r * NHID + quad * 8;
        #pragma unroll
        for (int ks = 0; ks < 4; ++ks) {
          pf[2 * ks]     = *(const float4*)(rp + ks * 32);
          pf[2 * ks + 1] = *(const float4*)(rp + ks * 32 + 4);
        }
      }
    }

    // ---- MFMA: 16 rows x 64 cols per wave ----
    f32x4 acc[4];
    #pragma unroll
    for (int nt = 0; nt < 4; ++nt)
      acc[nt] = (f32x4){0.f, 0.f, 0.f, 0.f};

    #pragma unroll
    for (int ks = 0; ks < 4; ++ks) {
      bf16x8 a = __builtin_bit_cast(bf16x8, af[ks]);
      #pragma unroll
      for (int nt = 0; nt < 4; ++nt)
        acc[nt] = __builtin_amdgcn_mfma_f32_16x16x32_bf16(a, bw[ks][nt], acc[nt], 0, 0, 0);
    }

    // ---- epilogue: +bias, cvt bf16, wave-local LDS repack, 16B stores ----
    // D layout: col = lane&15 (+nt*16), row = quad*4 + r
    #pragma unroll
    for (int nt = 0; nt < 4; ++nt)
      #pragma unroll
      for (int r = 0; r < 4; ++r)
        sC[w][quad * 4 + r][nt * 16 + m15] = f2bf(acc[nt][r] + bias[nt]);

    // wave-local write->read: compiler inserts lgkmcnt waits; no barrier needed
    const int rowbase = t * 16;
    #pragma unroll
    for (int p = 0; p < 2; ++p) {
      const int row  = p * 8 + (lane >> 3);
      const int node = rowbase + row;
      if (node < n_nodes) {
        u16x8 v = *(const u16x8*)&sC[w][row][(lane & 7) * 8];
        *(u16x8*)(AB + (size_t)node * 256 + w * 64 + (lane & 7) * 8) = v;
      }
    }
  }
}

// ============================================================================
// Phase 2: out[e] = sigmoid( relu(AB[x[e]][0:128] + AB[y[e]][128:256]) · W2 + b2 )
// 16 lanes per edge, 8 bf16 elems per lane, 4-edge unroll: 8 gathers/lane
// in flight. Zero LDS -> 8 blocks/CU -> 32 waves/CU of latency hiding.
// ============================================================================
__global__ __launch_bounds__(256, 4)
void edge_eval(const unsigned short* __restrict__ AB,
               const int* __restrict__ x_idx,
               const int* __restrict__ y_idx,
               const float* __restrict__ W2,
               const float* __restrict__ bias2,
               float* __restrict__ out,
               int n_edges)
{
  const int tid = threadIdx.x;
  const int g   = tid >> 4;   // group 0..15 within block
  const int l   = tid & 15;   // lane within group

  float w2[8];
  {
    float4 a = *(const float4*)(W2 + l * 8);
    float4 b = *(const float4*)(W2 + l * 8 + 4);
    w2[0] = a.x; w2[1] = a.y; w2[2] = a.z; w2[3] = a.w;
    w2[4] = b.x; w2[5] = b.y; w2[6] = b.z; w2[7] = b.w;
  }
  const float b2   = bias2[0];
  const int   last = n_edges - 1;
  const int   step = gridDim.x * 64;

  for (int base = blockIdx.x * 64; base < n_edges; base += step) {
    int e[4], xi[4], yi[4];
    #pragma unroll
    for (int k = 0; k < 4; ++k) {
      e[k] = base + 16 * k + g;
      int c = e[k] < last ? e[k] : last;
      xi[k] = x_idx[c];
      yi[k] = y_idx[c];
    }

    u16x8 ax[4], by[4];
    #pragma unroll
    for (int k = 0; k < 4; ++k) {
      ax[k] = *(const u16x8*)(AB + (size_t)xi[k] * 256 + l * 8);
      by[k] = *(const u16x8*)(AB + (size_t)yi[k] * 256 + 128 + l * 8);
    }

    float s[4] = {0.f, 0.f, 0.f, 0.f};
    #pragma unroll
    for (int j = 0; j < 8; ++j) {
      #pragma unroll
      for (int k = 0; k < 4; ++k) {
        float h = bf2f(ax[k][j]) + bf2f(by[k][j]);
        h = fmaxf(h, 0.f);
        s[k] = fmaf(h, w2[j], s[k]);
      }
    }
    #pragma unroll
    for (int d = 1; d < 16; d <<= 1) {
      #pragma unroll
      for (int k = 0; k < 4; ++k)
        s[k] += __shfl_xor(s[k], d);
    }
    if (l == 0) {
      #pragma unroll
      for (int k = 0; k < 4; ++k)
        if (e[k] < n_edges)
          out[e[k]] = 1.f / (1.f + __expf(-(s[k] + b2)));
    }
  }
}

// ============================================================================
// Fallback: previous fused kernel (used only if workspace is too small)
// ============================================================================
__global__ __launch_bounds__(256, 1)
void mlp_edge_decoder(const float* __restrict__ inputs,
                      const int* __restrict__ x_idx,
                      const int* __restrict__ y_idx,
                      const float* __restrict__ W1,
                      const float* __restrict__ bias1,
                      const float* __restrict__ W2,
                      const float* __restrict__ bias2,
                      float* __restrict__ out,
                      int n_edges)
{
  __shared__ __align__(16) unsigned short sW1T[NHID][LDK];
  __shared__ __align__(16) unsigned short sA[TILE_E][LDK];
  __shared__ float sB1[NHID];
  __shared__ float sW2[NHID];
  __shared__ float sRed[2][TILE_E];

  const int tid  = threadIdx.x;
  const int lane = tid & 63;
  const int wv   = tid >> 6;
  const int seg  = tid & 63;
  const int m15  = lane & 15;
  const int quad = lane >> 4;
  const int eh   = wv >> 1;
  const int ch   = wv & 1;

  for (int i = tid; i < 256 * NHID; i += 256) {
    int k = i >> 7;
    int n = i & 127;
    sW1T[n][k] = f2bf(W1[i]);
  }
  if (tid < NHID) { sB1[tid] = bias1[tid]; sW2[tid] = W2[tid]; }
  const float b2 = bias2[0];

  const int stride = gridDim.x * TILE_E;
  int ebase = blockIdx.x * TILE_E;

  float4 stage[32];
  #pragma unroll
  for (int j = 0; j < 32; ++j) {
    int e  = ebase + 4 * j + wv;
    int ec = (e < n_edges) ? e : 0;
    int idx = (seg < 32) ? x_idx[ec] : y_idx[ec];
    stage[j] = *(const float4*)(inputs + (size_t)idx * NHID + (seg & 31) * 4);
  }

  for (; ebase < n_edges; ebase += stride) {
    #pragma unroll
    for (int j = 0; j < 32; ++j) {
      int r = wv + 4 * j;
      ushort4 p;
      p.x = f2bf(stage[j].x);
      p.y = f2bf(stage[j].y);
      p.z = f2bf(stage[j].z);
      p.w = f2bf(stage[j].w);
      *(ushort4*)(&sA[r][seg * 4]) = p;
    }
    __syncthreads();

    {
      int nb = ebase + stride;
      if (nb < n_edges) {
        #pragma unroll
        for (int j = 0; j < 32; ++j) {
          int e  = nb + 4 * j + wv;
          int ec = (e < n_edges) ? e : 0;
          int idx = (seg < 32) ? x_idx[ec] : y_idx[ec];
          stage[j] = *(const float4*)(inputs + (size_t)idx * NHID + (seg & 31) * 4);
        }
      }
    }

    f32x4 acc[4][4];
    #pragma unroll
    for (int mt = 0; mt < 4; ++mt)
      #pragma unroll
      for (int nt = 0; nt < 4; ++nt)
        acc[mt][nt] = (f32x4){0.f, 0.f, 0.f, 0.f};

    #pragma unroll
    for (int ks = 0; ks < 8; ++ks) {
      bf16x8 af[4], bfr[4];
      #pragma unroll
      for (int mt = 0; mt < 4; ++mt)
        af[mt] = __builtin_bit_cast(bf16x8,
                   *(const u16x8*)(&sA[eh * 64 + mt * 16 + m15][ks * 32 + quad * 8]));
      #pragma unroll
      for (int nt = 0; nt < 4; ++nt)
        bfr[nt] = __builtin_bit_cast(bf16x8,
                   *(const u16x8*)(&sW1T[ch * 64 + nt * 16 + m15][ks * 32 + quad * 8]));
      #pragma unroll
      for (int mt = 0; mt < 4; ++mt)
        #pragma unroll
        for (int nt = 0; nt < 4; ++nt)
          acc[mt][nt] = __builtin_amdgcn_mfma_f32_16x16x32_bf16(af[mt], bfr[nt], acc[mt][nt], 0, 0, 0);
    }

    #pragma unroll
    for (int mt = 0; mt < 4; ++mt) {
      #pragma unroll
      for (int r = 0; r < 4; ++r) {
        float s = 0.f;
        #pragma unroll
        for (int nt = 0; nt < 4; ++nt) {
          int c = ch * 64 + nt * 16 + m15;
          float h = acc[mt][nt][r] + sB1[c];
          h = fmaxf(h, 0.f);
          s = fmaf(h, sW2[c], s);
        }
        s += __shfl_xor(s, 1);
        s += __shfl_xor(s, 2);
        s += __shfl_xor(s, 4);
        s += __shfl_xor(s, 8);
        if (m15 == 0) sRed[ch][eh * 64 + mt * 16 + quad * 4 + r] = s;
      }
    }
    __syncthreads();

    if (tid < TILE_E) {
      int e = ebase + tid;
      if (e < n_edges) {
        float s = sRed[0][tid] + sRed[1][tid] + b2;
        out[e] = 1.f / (1.f + __expf(-s));
      }
    }
  }
}

extern "C" void kernel_launch(void* const* d_in, const int* in_sizes, int n_in,
                              void* d_out, int out_size, void* d_ws, size_t ws_size,
                              hipStream_t stream) {
  const float* inputs = (const float*)d_in[0];
  const int*   x_idx  = (const int*)d_in[1];
  const int*   y_idx  = (const int*)d_in[2];
  const float* W1     = (const float*)d_in[3];
  const float* bias1  = (const float*)d_in[4];
  const float* W2     = (const float*)d_in[5];
  const float* bias2  = (const float*)d_in[6];
  float* out = (float*)d_out;
  const int n_edges = in_sizes[1];
  const int n_nodes = in_sizes[0] / NHID;

  const size_t need = (size_t)n_nodes * 256 * sizeof(unsigned short);
  if (d_ws != nullptr && ws_size >= need) {
    unsigned short* AB = (unsigned short*)d_ws;
    // Phase 1: node-level GEMM, 6250 16-row tiles over 1024 blocks, prefetch-pipelined
    hipLaunchKernelGGL(precompute_ab, dim3(1024), dim3(256), 0, stream,
                       inputs, W1, bias1, AB, n_nodes);
    // Phase 2: streaming gather + epilogue, 4-edge unroll
    hipLaunchKernelGGL(edge_eval, dim3(2048), dim3(256), 0, stream,
                       AB, x_idx, y_idx, W2, bias2, out, n_edges);
  } else {
    hipLaunchKernelGGL(mlp_edge_decoder, dim3(512), dim3(256), 0, stream,
                       inputs, x_idx, y_idx, W1, bias1, W2, bias2, out, n_edges);
  }
}

// Round 3
// 147.509 us; speedup vs baseline: 1.4771x; 1.0739x over previous
//
#include <hip/hip_runtime.h>
#include <math.h>

#define NHID 128
#define TILE_E 128
#define LDK 264   // padded K stride in bf16 elems (fallback kernel)
#define TILE_R 32 // phase-1 rows per block-iteration
#define LDA 136   // sA row stride in ushorts: 272 B = 17 x 16 B chunks -> conflict-free b128

typedef __bf16 bf16x8 __attribute__((ext_vector_type(8)));
typedef float f32x4 __attribute__((ext_vector_type(4)));
typedef unsigned short u16x8 __attribute__((ext_vector_type(8)));

__device__ __forceinline__ unsigned short f2bf(float f) {
  unsigned int u = __float_as_uint(f);
  u += 0x7fffu + ((u >> 16) & 1u);   // RNE
  return (unsigned short)(u >> 16);
}
__device__ __forceinline__ float bf2f(unsigned short u) {
  return __uint_as_float(((unsigned int)u) << 16);
}

// ============================================================================
// Phase 1: AB[node][0:128]  = inputs[node]·W1[0:128][:]   + bias1   (A half)
//          AB[node][128:256]= inputs[node]·W1[128:256][:]           (B half)
// 32-row tiles staged ONCE per block through a double-buffered bf16 LDS tile
// (each thread loads/converts a distinct 64B slice -> 4x less load-issue and
// 4x less f2bf VALU than per-wave redundant staging). One barrier per tile;
// next tile's global loads are issued before the barrier and fly across
// barrier + MFMA + epilogue. Wave w owns output cols w*64..w*64+63; W1
// fragments pinned in registers.
// ============================================================================
__global__ __launch_bounds__(256)
void precompute_ab(const float* __restrict__ inputs,
                   const float* __restrict__ W1,
                   const float* __restrict__ bias1,
                   unsigned short* __restrict__ AB,
                   int n_nodes)
{
  __shared__ __align__(16) unsigned short sA[2][TILE_R][LDA]; // 17.4 KB
  __shared__ __align__(16) unsigned short sC[4][16][72];      // 9.2 KB, wave-private repack

  const int tid  = threadIdx.x;
  const int lane = tid & 63;
  const int w    = tid >> 6;          // wave 0..3 -> output cols w*64..+63
  const int m15  = lane & 15;
  const int quad = lane >> 4;
  const int koff = (w >> 1) * NHID;   // W1 row offset: 0 (A half) or 128 (B half)
  const int cW   = (w & 1) * 64;      // W1 col base within half

  // ---- W1 B-fragments in registers: bw[ks][nt], loop-invariant ----
  bf16x8 bw[4][4];
  #pragma unroll
  for (int ks = 0; ks < 4; ++ks) {
    #pragma unroll
    for (int nt = 0; nt < 4; ++nt) {
      u16x8 t;
      #pragma unroll
      for (int j = 0; j < 8; ++j)
        t[j] = f2bf(W1[(size_t)(koff + ks * 32 + quad * 8 + j) * NHID + cW + nt * 16 + m15]);
      bw[ks][nt] = __builtin_bit_cast(bf16x8, t);
    }
  }

  // bias1 folded into the A half only (waves 0,1)
  float bias[4];
  #pragma unroll
  for (int nt = 0; nt < 4; ++nt)
    bias[nt] = (w < 2) ? bias1[w * 64 + nt * 16 + m15] : 0.f;

  // staging map: thread t covers 16 floats (64 B) of row t>>3
  const int srow = tid >> 3;          // 0..31
  const int scol = (tid & 7) * 16;    // logical col (floats == bf16 elems)

  const int ntiles = (n_nodes + TILE_R - 1) / TILE_R;
  const int stride = gridDim.x;
  int t = blockIdx.x;

  // ---- prologue: load tile t slice into regs ----
  float4 st0, st1, st2, st3;
  {
    int r = t * TILE_R + srow;
    if (r >= n_nodes) r = n_nodes - 1;
    if (r < 0) r = 0;
    const float* p = inputs + (size_t)r * NHID + scol;
    st0 = *(const float4*)(p);
    st1 = *(const float4*)(p + 4);
    st2 = *(const float4*)(p + 8);
    st3 = *(const float4*)(p + 12);
  }

  int cur = 0;
  for (; t < ntiles; t += stride) {
    // ---- stage_write: convert staged regs -> bf16 LDS tile ----
    {
      u16x8 w0, w1;
      w0[0] = f2bf(st0.x); w0[1] = f2bf(st0.y); w0[2] = f2bf(st0.z); w0[3] = f2bf(st0.w);
      w0[4] = f2bf(st1.x); w0[5] = f2bf(st1.y); w0[6] = f2bf(st1.z); w0[7] = f2bf(st1.w);
      w1[0] = f2bf(st2.x); w1[1] = f2bf(st2.y); w1[2] = f2bf(st2.z); w1[3] = f2bf(st2.w);
      w1[4] = f2bf(st3.x); w1[5] = f2bf(st3.y); w1[6] = f2bf(st3.z); w1[7] = f2bf(st3.w);
      *(u16x8*)&sA[cur][srow][scol]     = w0;
      *(u16x8*)&sA[cur][srow][scol + 8] = w1;
    }

    // ---- issue next tile's loads; they fly across barrier + MFMA + epilogue ----
    {
      int tn = t + stride;
      if (tn < ntiles) {
        int r = tn * TILE_R + srow;
        if (r >= n_nodes) r = n_nodes - 1;
        const float* p = inputs + (size_t)r * NHID + scol;
        st0 = *(const float4*)(p);
        st1 = *(const float4*)(p + 4);
        st2 = *(const float4*)(p + 8);
        st3 = *(const float4*)(p + 12);
      }
    }

    __syncthreads();   // sA[cur] visible; (writes to sA[cur^1] next iter are disjoint)

    const int rowbase = t * TILE_R;
    #pragma unroll
    for (int mt = 0; mt < 2; ++mt) {
      // A-fragments from LDS (conflict-free: 17x16B row chunks)
      bf16x8 af[4];
      #pragma unroll
      for (int ks = 0; ks < 4; ++ks)
        af[ks] = __builtin_bit_cast(bf16x8,
                   *(const u16x8*)(&sA[cur][mt * 16 + m15][ks * 32 + quad * 8]));

      f32x4 acc[4];
      #pragma unroll
      for (int nt = 0; nt < 4; ++nt)
        acc[nt] = (f32x4){0.f, 0.f, 0.f, 0.f};

      #pragma unroll
      for (int ks = 0; ks < 4; ++ks)
        #pragma unroll
        for (int nt = 0; nt < 4; ++nt)
          acc[nt] = __builtin_amdgcn_mfma_f32_16x16x32_bf16(af[ks], bw[ks][nt], acc[nt], 0, 0, 0);

      // epilogue: +bias, cvt bf16, wave-private LDS repack, 16B stores
      // D layout: col = lane&15 (+nt*16), row = quad*4 + r
      #pragma unroll
      for (int nt = 0; nt < 4; ++nt)
        #pragma unroll
        for (int r = 0; r < 4; ++r)
          sC[w][quad * 4 + r][nt * 16 + m15] = f2bf(acc[nt][r] + bias[nt]);

      #pragma unroll
      for (int p = 0; p < 2; ++p) {
        const int row  = p * 8 + (lane >> 3);
        const int node = rowbase + mt * 16 + row;
        if (node < n_nodes) {
          u16x8 v = *(const u16x8*)&sC[w][row][(lane & 7) * 8];
          *(u16x8*)(AB + (size_t)node * 256 + w * 64 + (lane & 7) * 8) = v;
        }
      }
    }
    cur ^= 1;
  }
}

// ============================================================================
// Phase 2: out[e] = sigmoid( relu(AB[x[e]][0:128] + AB[y[e]][128:256]) · W2 + b2 )
// 16 lanes per edge, 8 bf16 elems per lane, 4-edge unroll: 8 gathers/lane
// in flight. Zero LDS. Measured ~5.8 TB/s cache-side gather BW (bytes are
// algorithmically forced: 512 B/edge) -- left unchanged this round.
// ============================================================================
__global__ __launch_bounds__(256, 4)
void edge_eval(const unsigned short* __restrict__ AB,
               const int* __restrict__ x_idx,
               const int* __restrict__ y_idx,
               const float* __restrict__ W2,
               const float* __restrict__ bias2,
               float* __restrict__ out,
               int n_edges)
{
  const int tid = threadIdx.x;
  const int g   = tid >> 4;   // group 0..15 within block
  const int l   = tid & 15;   // lane within group

  float w2[8];
  {
    float4 a = *(const float4*)(W2 + l * 8);
    float4 b = *(const float4*)(W2 + l * 8 + 4);
    w2[0] = a.x; w2[1] = a.y; w2[2] = a.z; w2[3] = a.w;
    w2[4] = b.x; w2[5] = b.y; w2[6] = b.z; w2[7] = b.w;
  }
  const float b2   = bias2[0];
  const int   last = n_edges - 1;
  const int   step = gridDim.x * 64;

  for (int base = blockIdx.x * 64; base < n_edges; base += step) {
    int e[4], xi[4], yi[4];
    #pragma unroll
    for (int k = 0; k < 4; ++k) {
      e[k] = base + 16 * k + g;
      int c = e[k] < last ? e[k] : last;
      xi[k] = x_idx[c];
      yi[k] = y_idx[c];
    }

    u16x8 ax[4], by[4];
    #pragma unroll
    for (int k = 0; k < 4; ++k) {
      ax[k] = *(const u16x8*)(AB + (size_t)xi[k] * 256 + l * 8);
      by[k] = *(const u16x8*)(AB + (size_t)yi[k] * 256 + 128 + l * 8);
    }

    float s[4] = {0.f, 0.f, 0.f, 0.f};
    #pragma unroll
    for (int j = 0; j < 8; ++j) {
      #pragma unroll
      for (int k = 0; k < 4; ++k) {
        float h = bf2f(ax[k][j]) + bf2f(by[k][j]);
        h = fmaxf(h, 0.f);
        s[k] = fmaf(h, w2[j], s[k]);
      }
    }
    #pragma unroll
    for (int d = 1; d < 16; d <<= 1) {
      #pragma unroll
      for (int k = 0; k < 4; ++k)
        s[k] += __shfl_xor(s[k], d);
    }
    if (l == 0) {
      #pragma unroll
      for (int k = 0; k < 4; ++k)
        if (e[k] < n_edges)
          out[e[k]] = 1.f / (1.f + __expf(-(s[k] + b2)));
    }
  }
}

// ============================================================================
// Fallback: previous fused kernel (used only if workspace is too small)
// ============================================================================
__global__ __launch_bounds__(256, 1)
void mlp_edge_decoder(const float* __restrict__ inputs,
                      const int* __restrict__ x_idx,
                      const int* __restrict__ y_idx,
                      const float* __restrict__ W1,
                      const float* __restrict__ bias1,
                      const float* __restrict__ W2,
                      const float* __restrict__ bias2,
                      float* __restrict__ out,
                      int n_edges)
{
  __shared__ __align__(16) unsigned short sW1T[NHID][LDK];
  __shared__ __align__(16) unsigned short sA[TILE_E][LDK];
  __shared__ float sB1[NHID];
  __shared__ float sW2[NHID];
  __shared__ float sRed[2][TILE_E];

  const int tid  = threadIdx.x;
  const int lane = tid & 63;
  const int wv   = tid >> 6;
  const int seg  = tid & 63;
  const int m15  = lane & 15;
  const int quad = lane >> 4;
  const int eh   = wv >> 1;
  const int ch   = wv & 1;

  for (int i = tid; i < 256 * NHID; i += 256) {
    int k = i >> 7;
    int n = i & 127;
    sW1T[n][k] = f2bf(W1[i]);
  }
  if (tid < NHID) { sB1[tid] = bias1[tid]; sW2[tid] = W2[tid]; }
  const float b2 = bias2[0];

  const int stride = gridDim.x * TILE_E;
  int ebase = blockIdx.x * TILE_E;

  float4 stage[32];
  #pragma unroll
  for (int j = 0; j < 32; ++j) {
    int e  = ebase + 4 * j + wv;
    int ec = (e < n_edges) ? e : 0;
    int idx = (seg < 32) ? x_idx[ec] : y_idx[ec];
    stage[j] = *(const float4*)(inputs + (size_t)idx * NHID + (seg & 31) * 4);
  }

  for (; ebase < n_edges; ebase += stride) {
    #pragma unroll
    for (int j = 0; j < 32; ++j) {
      int r = wv + 4 * j;
      ushort4 p;
      p.x = f2bf(stage[j].x);
      p.y = f2bf(stage[j].y);
      p.z = f2bf(stage[j].z);
      p.w = f2bf(stage[j].w);
      *(ushort4*)(&sA[r][seg * 4]) = p;
    }
    __syncthreads();

    {
      int nb = ebase + stride;
      if (nb < n_edges) {
        #pragma unroll
        for (int j = 0; j < 32; ++j) {
          int e  = nb + 4 * j + wv;
          int ec = (e < n_edges) ? e : 0;
          int idx = (seg < 32) ? x_idx[ec] : y_idx[ec];
          stage[j] = *(const float4*)(inputs + (size_t)idx * NHID + (seg & 31) * 4);
        }
      }
    }

    f32x4 acc[4][4];
    #pragma unroll
    for (int mt = 0; mt < 4; ++mt)
      #pragma unroll
      for (int nt = 0; nt < 4; ++nt)
        acc[mt][nt] = (f32x4){0.f, 0.f, 0.f, 0.f};

    #pragma unroll
    for (int ks = 0; ks < 8; ++ks) {
      bf16x8 af[4], bfr[4];
      #pragma unroll
      for (int mt = 0; mt < 4; ++mt)
        af[mt] = __builtin_bit_cast(bf16x8,
                   *(const u16x8*)(&sA[eh * 64 + mt * 16 + m15][ks * 32 + quad * 8]));
      #pragma unroll
      for (int nt = 0; nt < 4; ++nt)
        bfr[nt] = __builtin_bit_cast(bf16x8,
                   *(const u16x8*)(&sW1T[ch * 64 + nt * 16 + m15][ks * 32 + quad * 8]));
      #pragma unroll
      for (int mt = 0; mt < 4; ++mt)
        #pragma unroll
        for (int nt = 0; nt < 4; ++nt)
          acc[mt][nt] = __builtin_amdgcn_mfma_f32_16x16x32_bf16(af[mt], bfr[nt], acc[mt][nt], 0, 0, 0);
    }

    #pragma unroll
    for (int mt = 0; mt < 4; ++mt) {
      #pragma unroll
      for (int r = 0; r < 4; ++r) {
        float s = 0.f;
        #pragma unroll
        for (int nt = 0; nt < 4; ++nt) {
          int c = ch * 64 + nt * 16 + m15;
          float h = acc[mt][nt][r] + sB1[c];
          h = fmaxf(h, 0.f);
          s = fmaf(h, sW2[c], s);
        }
        s += __shfl_xor(s, 1);
        s += __shfl_xor(s, 2);
        s += __shfl_xor(s, 4);
        s += __shfl_xor(s, 8);
        if (m15 == 0) sRed[ch][eh * 64 + mt * 16 + quad * 4 + r] = s;
      }
    }
    __syncthreads();

    if (tid < TILE_E) {
      int e = ebase + tid;
      if (e < n_edges) {
        float s = sRed[0][tid] + sRed[1][tid] + b2;
        out[e] = 1.f / (1.f + __expf(-s));
      }
    }
  }
}

extern "C" void kernel_launch(void* const* d_in, const int* in_sizes, int n_in,
                              void* d_out, int out_size, void* d_ws, size_t ws_size,
                              hipStream_t stream) {
  const float* inputs = (const float*)d_in[0];
  const int*   x_idx  = (const int*)d_in[1];
  const int*   y_idx  = (const int*)d_in[2];
  const float* W1     = (const float*)d_in[3];
  const float* bias1  = (const float*)d_in[4];
  const float* W2     = (const float*)d_in[5];
  const float* bias2  = (const float*)d_in[6];
  float* out = (float*)d_out;
  const int n_edges = in_sizes[1];
  const int n_nodes = in_sizes[0] / NHID;

  const size_t need = (size_t)n_nodes * 256 * sizeof(unsigned short);
  if (d_ws != nullptr && ws_size >= need) {
    unsigned short* AB = (unsigned short*)d_ws;
    // Phase 1: 32-row tiles, 3 tiles/block (balanced): grid = ceil(ntiles/3)
    const int ntiles = (n_nodes + TILE_R - 1) / TILE_R;
    int grid1 = (ntiles + 2) / 3;
    if (grid1 < 1) grid1 = 1;
    hipLaunchKernelGGL(precompute_ab, dim3(grid1), dim3(256), 0, stream,
                       inputs, W1, bias1, AB, n_nodes);
    // Phase 2: streaming gather + epilogue, 4-edge unroll
    hipLaunchKernelGGL(edge_eval, dim3(2048), dim3(256), 0, stream,
                       AB, x_idx, y_idx, W2, bias2, out, n_edges);
  } else {
    hipLaunchKernelGGL(mlp_edge_decoder, dim3(512), dim3(256), 0, stream,
                       inputs, x_idx, y_idx, W1, bias1, W2, bias2, out, n_edges);
  }
}